// Round 8
// baseline (525.738 us; speedup 1.0000x reference)
//
#include <hip/hip_runtime.h>
#include <hip/hip_bf16.h>

// Problem constants: B=4, L=1024, H=1024, E=16, NH=16, D=64
#define MTOK   4096     // B*L rows of the big GEMMs
#define HID    1024     // H
#define NSUB   65536    // MTOK*NH sub-tokens
#define DDIM   64       // head_dim == expert dim
#define NEXP   16

#define CAP    NSUB     // per-expert list capacity — overflow impossible
#define T_TILE 64       // tokens per expert_gemm tile

// LDS row stride (shorts) for MFMA-GEMM tiles: 32 data + 8 pad = 80 B = 5*16B.
// Keeps ds_read_b128 16B-aligned; quarter-wave's 16 row-reads spread
// 2 lanes/bank (free, m136) instead of 8-way at a 64 B stride.
#define KSTR   40

typedef float  f32x4  __attribute__((ext_vector_type(4)));
typedef short  s16x8  __attribute__((ext_vector_type(8)));

// fp32 -> bf16 bits, round-to-nearest-even (inputs finite)
static __device__ __forceinline__ unsigned short f2bf(float f) {
    union { float f; unsigned u; } c; c.f = f;
    return (unsigned short)((c.u + 0x7fffu + ((c.u >> 16) & 1u)) >> 16);
}

// ---------------------------------------------------------------------------
__global__ void zero_cnt(int* __restrict__ cnt) { cnt[threadIdx.x] = 0; }

// ---------------------------------------------------------------------------
// prep_F: F[k][g*16+e] = sum_d Wmh[k][g*64+d] * emb[d][e]   (k = 0..1023)
//         F[1024][ge]  = sum_d bmh[g*64+d]   * emb[d][e]    (fbias row)
// Exact-math identity: logits = h@emb = x@F + fbias. fp32 throughout, so
// routing accuracy matches the previously-passing fp32 path (~1e-5 logit).
// ---------------------------------------------------------------------------
__global__ __launch_bounds__(256) void prep_F(
    const float* __restrict__ Wmh, const float* __restrict__ bmh,
    const float* __restrict__ emb, float* __restrict__ F)
{
    const int k = blockIdx.x;                 // 0..1024 (1024 = bias row)
    const int g = threadIdx.x >> 4;
    const int e = threadIdx.x & 15;
    const float* src = (k < HID) ? &Wmh[(size_t)k * HID] : bmh;
    float s = 0.f;
#pragma unroll
    for (int d = 0; d < DDIM; d++)
        s = fmaf(src[g * DDIM + d], emb[d * NEXP + e], s);
    F[(size_t)k * 256 + threadIdx.x] = s;
}

// ---------------------------------------------------------------------------
// Router on precise logits: lg = x_row @ F[:, g*16..] + fbias. Softmax,
// top-2 (raw probs, stable lowest-index tie-break matching jax.lax.top_k),
// LDS-aggregated compaction of (token|slot<<16) into per-expert lists.
// F reads are 16-lane broadcasts of L2-resident data; no LDS staging needed.
// ---------------------------------------------------------------------------
__global__ __launch_bounds__(128) void router_F(
    const float* __restrict__ x, const float* __restrict__ F,
    float2* __restrict__ rw, int* __restrict__ cnt, int* __restrict__ lists)
{
    __shared__ int lcnt[NEXP], gbase[NEXP];
    const int tid = threadIdx.x;
    if (tid < NEXP) lcnt[tid] = 0;
    __syncthreads();

    const int n = blockIdx.x * 128 + tid;     // sub-token id
    const int t = n >> 4;                     // token row in x
    const int g = n & 15;                     // head
    const float* xr = x + (size_t)t * HID;

    float lg[NEXP];
    // init with fbias row (row 1024 of F)
    *(float4*)&lg[0]  = *(const float4*)&F[(size_t)HID * 256 + g * 16 + 0];
    *(float4*)&lg[4]  = *(const float4*)&F[(size_t)HID * 256 + g * 16 + 4];
    *(float4*)&lg[8]  = *(const float4*)&F[(size_t)HID * 256 + g * 16 + 8];
    *(float4*)&lg[12] = *(const float4*)&F[(size_t)HID * 256 + g * 16 + 12];

#pragma unroll 4
    for (int k = 0; k < HID; k++) {
        const float xv = xr[k];
        const float* Fr = &F[(size_t)k * 256 + g * 16];
        const float4 f0 = *(const float4*)&Fr[0];
        const float4 f1 = *(const float4*)&Fr[4];
        const float4 f2 = *(const float4*)&Fr[8];
        const float4 f3 = *(const float4*)&Fr[12];
        lg[0]  = fmaf(xv, f0.x, lg[0]);  lg[1]  = fmaf(xv, f0.y, lg[1]);
        lg[2]  = fmaf(xv, f0.z, lg[2]);  lg[3]  = fmaf(xv, f0.w, lg[3]);
        lg[4]  = fmaf(xv, f1.x, lg[4]);  lg[5]  = fmaf(xv, f1.y, lg[5]);
        lg[6]  = fmaf(xv, f1.z, lg[6]);  lg[7]  = fmaf(xv, f1.w, lg[7]);
        lg[8]  = fmaf(xv, f2.x, lg[8]);  lg[9]  = fmaf(xv, f2.y, lg[9]);
        lg[10] = fmaf(xv, f2.z, lg[10]); lg[11] = fmaf(xv, f2.w, lg[11]);
        lg[12] = fmaf(xv, f3.x, lg[12]); lg[13] = fmaf(xv, f3.y, lg[13]);
        lg[14] = fmaf(xv, f3.z, lg[14]); lg[15] = fmaf(xv, f3.w, lg[15]);
    }

    float m = lg[0];
#pragma unroll
    for (int e = 1; e < NEXP; e++) m = fmaxf(m, lg[e]);
    float p[NEXP], den = 0.f;
#pragma unroll
    for (int e = 0; e < NEXP; e++) { p[e] = expf(lg[e] - m); den += p[e]; }
    int i1 = 0; float v1 = p[0];
#pragma unroll
    for (int e = 1; e < NEXP; e++) if (p[e] > v1) { v1 = p[e]; i1 = e; }
    int i2 = (i1 == 0) ? 1 : 0; float v2 = p[i2];
#pragma unroll
    for (int e = 0; e < NEXP; e++)
        if (e != i1 && e != ((i1 == 0) ? 1 : 0) && p[e] > v2) { v2 = p[e]; i2 = e; }

    const float invd = 1.f / den;
    rw[n] = make_float2(v1 * invd, v2 * invd);

    // LDS-aggregated compaction (i1 != i2 guarantees distinct slots)
    const int lp1 = atomicAdd(&lcnt[i1], 1);
    const int lp2 = atomicAdd(&lcnt[i2], 1);
    __syncthreads();
    if (tid < NEXP) gbase[tid] = atomicAdd(&cnt[tid], lcnt[tid]);
    __syncthreads();
    lists[i1 * CAP + gbase[i1] + lp1] = n;              // slot 0
    lists[i2 * CAP + gbase[i2] + lp2] = n | 0x10000;    // slot 1
}

// ---------------------------------------------------------------------------
// Expert GEMM over compacted lists (unchanged from the passing version).
// ---------------------------------------------------------------------------
__global__ __launch_bounds__(256) void expert_gemm(
    const float* __restrict__ h, const int* __restrict__ cnt,
    const int* __restrict__ lists, const float2* __restrict__ rw,
    const float* __restrict__ w1, const float* __restrict__ b1,
    const float* __restrict__ w2, const float* __restrict__ b2,
    const float* __restrict__ w3, const float* __restrict__ b3,
    float* __restrict__ pa, float* __restrict__ pb)
{
    const int e    = blockIdx.x;
    const int base = blockIdx.y * T_TILE;
    const int ne   = cnt[e];
    if (base >= ne) return;
    const int nt = min(T_TILE, ne - base);

    __shared__ float act0[T_TILE][DDIM];
    __shared__ float act1[T_TILE][DDIM];
    __shared__ int   toks[T_TILE];

    const int tid  = threadIdx.x;
    const int wave = tid >> 6;
    const int lane = tid & 63;
    const int jA   = lane & 31;
    const int half = lane >> 5;

    if (tid < T_TILE) toks[tid] = (tid < nt) ? lists[e * CAP + base + tid] : 0;
    __syncthreads();

#pragma unroll
    for (int p = 0; p < T_TILE / 16; p++) {
        const int r = p * 16 + (tid >> 4);
        const int c = (tid & 15) * 4;
        if (r < nt) {
            const int t = toks[r] & 0xffff;
            *(float4*)&act0[r][c] = *(const float4*)&h[(size_t)t * DDIM + c];
        }
    }
    __syncthreads();

    float wa[DDIM], wb[DDIM];

#define LOAD_W(WP, BP, BA, BB) do {                                          \
        const float* wp_ = (WP) + (size_t)e * DDIM * DDIM;                   \
        _Pragma("unroll")                                                    \
        for (int i = 0; i < DDIM; i++) {                                     \
            wa[i] = wp_[i * DDIM + jA];                                      \
            wb[i] = wp_[i * DDIM + jA + 32];                                 \
        }                                                                    \
        BA = (BP)[e * DDIM + jA]; BB = (BP)[e * DDIM + jA + 32];             \
    } while (0)

#define DOT2(SRC, TR, AA, BB2) do {                                          \
        float a0 = 0.f, a1s = 0.f, b0 = 0.f, b1s = 0.f;                      \
        _Pragma("unroll")                                                    \
        for (int i = 0; i < 32; i += 4) {                                    \
            const float4 v = *(const float4*)&SRC[TR][i];                    \
            a0 = fmaf(v.x, wa[i + 0], a0); b0 = fmaf(v.x, wb[i + 0], b0);    \
            a0 = fmaf(v.y, wa[i + 1], a0); b0 = fmaf(v.y, wb[i + 1], b0);    \
            a0 = fmaf(v.z, wa[i + 2], a0); b0 = fmaf(v.z, wb[i + 2], b0);    \
            a0 = fmaf(v.w, wa[i + 3], a0); b0 = fmaf(v.w, wb[i + 3], b0);    \
        }                                                                    \
        _Pragma("unroll")                                                    \
        for (int i = 32; i < 64; i += 4) {                                   \
            const float4 v = *(const float4*)&SRC[TR][i];                    \
            a1s = fmaf(v.x, wa[i + 0], a1s); b1s = fmaf(v.x, wb[i + 0], b1s);\
            a1s = fmaf(v.y, wa[i + 1], a1s); b1s = fmaf(v.y, wb[i + 1], b1s);\
            a1s = fmaf(v.z, wa[i + 2], a1s); b1s = fmaf(v.z, wb[i + 2], b1s);\
            a1s = fmaf(v.w, wa[i + 3], a1s); b1s = fmaf(v.w, wb[i + 3], b1s);\
        }                                                                    \
        AA = a0 + a1s; BB2 = b0 + b1s;                                       \
    } while (0)

    float ba, bb;
    LOAD_W(w1, b1, ba, bb);
#pragma unroll
    for (int p = 0; p < T_TILE / 8; p++) {
        const int tr = p * 8 + wave * 2 + half;
        float aA, aB;
        DOT2(act0, tr, aA, aB);
        act1[tr][jA]      = fmaxf(aA + ba, 0.f);
        act1[tr][jA + 32] = fmaxf(aB + bb, 0.f);
    }
    LOAD_W(w2, b2, ba, bb);
#pragma unroll
    for (int p = 0; p < T_TILE / 8; p++) {
        const int tr = p * 8 + wave * 2 + half;
        float aA, aB;
        DOT2(act1, tr, aA, aB);
        act0[tr][jA]      = fmaxf(aA + ba, 0.f);
        act0[tr][jA + 32] = fmaxf(aB + bb, 0.f);
    }
    LOAD_W(w3, b3, ba, bb);
#pragma unroll
    for (int p = 0; p < T_TILE / 8; p++) {
        const int tr = p * 8 + wave * 2 + half;
        float aA, aB;
        DOT2(act0, tr, aA, aB);
        if (tr < nt) {
            const int en = toks[tr];
            const int t  = en & 0xffff;
            const float2 wv = rw[t];
            const float wgt = (en & 0x10000) ? wv.y : wv.x;
            float* dst = (en & 0x10000) ? pb : pa;
            dst[(size_t)t * DDIM + jA]      = (aA + ba) * wgt;
            dst[(size_t)t * DDIM + jA + 32] = (aB + bb) * wgt;
        }
    }
#undef LOAD_W
#undef DOT2
}

// ---------------------------------------------------------------------------
// Transpose + bf16-convert: WT[n][k] = bf16(W[k][n]).  64x64 tiles.
// ---------------------------------------------------------------------------
__global__ __launch_bounds__(256) void transpose_bf16(
    const float* __restrict__ W, unsigned short* __restrict__ WT, int K, int N)
{
    __shared__ float tile[64][65];
    const int k0 = blockIdx.x * 64;
    const int n0 = blockIdx.y * 64;
    const int tid = threadIdx.x;
    const int tr = tid >> 4;
    const int tc = (tid & 15) * 4;
#pragma unroll
    for (int p = 0; p < 4; p++) {
        const int r = p * 16 + tr;
        const float4 v = *(const float4*)&W[(size_t)(k0 + r) * N + n0 + tc];
        tile[r][tc + 0] = v.x; tile[r][tc + 1] = v.y;
        tile[r][tc + 2] = v.z; tile[r][tc + 3] = v.w;
    }
    __syncthreads();
#pragma unroll
    for (int p = 0; p < 4; p++) {
        const int n = p * 16 + tr;
        ushort4 o;
        o.x = f2bf(tile[tc + 0][n]); o.y = f2bf(tile[tc + 1][n]);
        o.z = f2bf(tile[tc + 2][n]); o.w = f2bf(tile[tc + 3][n]);
        *(ushort4*)&WT[(size_t)(n0 + n) * K + k0 + tc] = o;
    }
}

// ---------------------------------------------------------------------------
// MFMA GEMM: C[M,N] = A[M,K] @ W[K,N] + bias, W given as WT[n][k] bf16.
// COMBINE: A := Aa + Ab elementwise during bf16 staging (GEMM2's top-2 fuse).
// 128x128 tile, 4 waves each 64x64 (4x4 frags of 16x16x32 bf16 MFMA).
// Fragment mapping (m89-verified): A lane l holds A[l&15][(l>>4)*8+j];
// B lane l holds B[(l>>4)*8+j][l&15]; D col=l&15, row=(l>>4)*4+reg.
// ---------------------------------------------------------------------------
template <bool COMBINE>
__global__ __launch_bounds__(256) void gemm_mfma(
    const float* __restrict__ Aa, const float* __restrict__ Ab,
    const unsigned short* __restrict__ WT, const float* __restrict__ bias,
    float* __restrict__ C, int M, int N, int K)
{
    __shared__ unsigned short A_bf[128][KSTR];   // [m][k] (+pad)
    __shared__ unsigned short B_bf[128][KSTR];   // [n][k] (+pad)

    const int tid  = threadIdx.x;
    const int bm   = blockIdx.y * 128;
    const int bn   = blockIdx.x * 128;
    const int wave = tid >> 6;
    const int lane = tid & 63;
    const int wm   = (wave >> 1) * 64;
    const int wn   = (wave & 1) * 64;
    const int r16  = lane & 15;
    const int g8   = (lane >> 4) * 8;

    const int srow = tid >> 1;
    const int skh  = (tid & 1) * 16;

    f32x4 acc[4][4];
#pragma unroll
    for (int i = 0; i < 4; i++)
#pragma unroll
        for (int j = 0; j < 4; j++) acc[i][j] = (f32x4){0.f, 0.f, 0.f, 0.f};

    for (int k0 = 0; k0 < K; k0 += 32) {
        {
            const float* pA = Aa + (size_t)(bm + srow) * K + k0 + skh;
            const float* pB = COMBINE ? Ab + (size_t)(bm + srow) * K + k0 + skh
                                      : nullptr;
            unsigned short tmp[16];
#pragma unroll
            for (int q = 0; q < 4; q++) {
                float4 va = *(const float4*)&pA[q * 4];
                if constexpr (COMBINE) {
                    const float4 vb = *(const float4*)&pB[q * 4];
                    va.x += vb.x; va.y += vb.y; va.z += vb.z; va.w += vb.w;
                }
                tmp[q * 4 + 0] = f2bf(va.x);
                tmp[q * 4 + 1] = f2bf(va.y);
                tmp[q * 4 + 2] = f2bf(va.z);
                tmp[q * 4 + 3] = f2bf(va.w);
            }
            *(s16x8*)&A_bf[srow][skh]     = *(s16x8*)&tmp[0];
            *(s16x8*)&A_bf[srow][skh + 8] = *(s16x8*)&tmp[8];
        }
        {
            const unsigned short* pW = WT + (size_t)(bn + srow) * K + k0 + skh;
            *(s16x8*)&B_bf[srow][skh]     = *(const s16x8*)&pW[0];
            *(s16x8*)&B_bf[srow][skh + 8] = *(const s16x8*)&pW[8];
        }
        __syncthreads();

        s16x8 av[4], bv[4];
#pragma unroll
        for (int i = 0; i < 4; i++)
            av[i] = *(s16x8*)&A_bf[wm + i * 16 + r16][g8];
#pragma unroll
        for (int j = 0; j < 4; j++)
            bv[j] = *(s16x8*)&B_bf[wn + j * 16 + r16][g8];
#pragma unroll
        for (int i = 0; i < 4; i++)
#pragma unroll
            for (int j = 0; j < 4; j++)
                acc[i][j] = __builtin_amdgcn_mfma_f32_16x16x32_bf16(
                    av[i], bv[j], acc[i][j], 0, 0, 0);
        __syncthreads();
    }

#pragma unroll
    for (int i = 0; i < 4; i++)
#pragma unroll
        for (int j = 0; j < 4; j++) {
            const int col = bn + wn + j * 16 + r16;
            const float bv2 = bias[col];
#pragma unroll
            for (int r = 0; r < 4; r++) {
                const int row = bm + wm + i * 16 + (lane >> 4) * 4 + r;
                C[(size_t)row * N + col] = acc[i][j][r] + bv2;
            }
        }
}

// ---------------------------------------------------------------------------
extern "C" void kernel_launch(void* const* d_in, const int* in_sizes, int n_in,
                              void* d_out, int out_size, void* d_ws, size_t ws_size,
                              hipStream_t stream)
{
    const float* x    = (const float*)d_in[0];
    const float* Wmh  = (const float*)d_in[1];
    const float* bmh  = (const float*)d_in[2];
    const float* emb  = (const float*)d_in[3];
    const float* w1   = (const float*)d_in[4];
    const float* b1   = (const float*)d_in[5];
    const float* w2   = (const float*)d_in[6];
    const float* b2   = (const float*)d_in[7];
    const float* w3   = (const float*)d_in[8];
    const float* b3   = (const float*)d_in[9];
    const float* Wm   = (const float*)d_in[10];
    const float* bm   = (const float*)d_in[11];
    float* out = (float*)d_out;

    // ws (proven 48.5 MB layout): h 16M | pa 16M | pb 16M | rw 512K | cnt 1K.
    // WmT (2MB, for GEMM2) aliases h after expert_gemm consumes it.
    // d_out scratch (all dead before gemm2's epilogue overwrites d_out):
    //   lists @0 (4MB) | F @8M (1.05MB) | WmhT @12M (2MB).
    char* ws = (char*)d_ws;
    float*  h     = (float*)(ws);
    float*  pa    = (float*)(ws + (size_t)(16 << 20));
    float*  pb    = (float*)(ws + (size_t)(32 << 20));
    float2* rwp   = (float2*)(ws + (size_t)(48 << 20));
    int*    cntp  = (int*)  (ws + (size_t)(48 << 20) + (NSUB * 8));
    unsigned short* WmT = (unsigned short*)(ws);

    char* dob = (char*)d_out;
    int*            lists = (int*)dob;
    float*          F     = (float*)(dob + (size_t)(8 << 20));
    unsigned short* WmhT  = (unsigned short*)(dob + (size_t)(12 << 20));

    // 1) WmhT[n][k] = bf16(Wmh[k][n]);  F = [Wmh;bmh] @ emb (per-head, fp32)
    transpose_bf16<<<dim3(HID / 64, HID / 64), 256, 0, stream>>>(
        Wmh, WmhT, HID, HID);
    prep_F<<<HID + 1, 256, 0, stream>>>(Wmh, bmh, emb, F);

    // 2) h = x @ Wmh + bmh   (bf16 MFMA; h feeds only the expert MLP)
    gemm_mfma<false><<<dim3(HID / 128, MTOK / 128), 256, 0, stream>>>(
        x, nullptr, WmhT, bmh, h, MTOK, HID, HID);

    // 3) route on precise fp32 logits = x@F + fbias; compact per-expert lists
    zero_cnt<<<1, NEXP, 0, stream>>>(cntp);
    router_F<<<NSUB / 128, 128, 0, stream>>>(x, F, rwp, cntp, lists);

    // 4) sparse expert MLP -> slot planes pa, pb (h consumed here)
    expert_gemm<<<dim3(NEXP, CAP / T_TILE), 256, 0, stream>>>(
        h, cntp, lists, rwp, w1, b1, w2, b2, w3, b3, pa, pb);

    // 5) WmT[n][k] = bf16(Wm[k][n])   (clobbers h — now dead)
    transpose_bf16<<<dim3(HID / 64, HID / 64), 256, 0, stream>>>(
        Wm, WmT, HID, HID);

    // 6) out = (pa + pb) @ Wm + bm   (bf16 MFMA, fused top-2 combine)
    gemm_mfma<true><<<dim3(HID / 128, MTOK / 128), 256, 0, stream>>>(
        pa, pb, WmT, bm, out, MTOK, HID, HID);
}

// Round 10
// 492.963 us; speedup vs baseline: 1.0665x; 1.0665x over previous
//
#include <hip/hip_runtime.h>
#include <hip/hip_bf16.h>

// Problem constants: B=4, L=1024, H=1024, E=16, NH=16, D=64
#define MTOK   4096     // B*L rows of the big GEMMs
#define HID    1024     // H
#define NSUB   65536    // MTOK*NH sub-tokens
#define DDIM   64       // head_dim == expert dim
#define NEXP   16

#define CAP    NSUB     // per-expert list capacity — overflow impossible
#define T_TILE 64       // tokens per expert_gemm tile

// LDS row stride (shorts) for MFMA-GEMM tiles: 32 data + 8 pad = 80 B = 5*16B.
// Keeps ds_read_b128 16B-aligned; 16 row-reads spread 2 lanes/bank (m136).
#define KSTR   40

typedef float  f32x4  __attribute__((ext_vector_type(4)));
typedef short  s16x8  __attribute__((ext_vector_type(8)));

// fp32 -> bf16 bits, round-to-nearest-even (inputs finite)
static __device__ __forceinline__ unsigned short f2bf(float f) {
    union { float f; unsigned u; } c; c.f = f;
    return (unsigned short)((c.u + 0x7fffu + ((c.u >> 16) & 1u)) >> 16);
}

// ---------------------------------------------------------------------------
// prep_F: F[k][g*16+e] = sum_d Wmh[k][g*64+d] * emb[d][e]   (k = 0..1023)
//         F[1024][ge]  = sum_d bmh[g*64+d]   * emb[d][e]    (fbias row)
// Exact identity: logits = h@emb = x@F + fbias, fp32 throughout.
// Block 0 also zeroes the compaction counters (consumed later by router).
// ---------------------------------------------------------------------------
__global__ __launch_bounds__(256) void prep_F(
    const float* __restrict__ Wmh, const float* __restrict__ bmh,
    const float* __restrict__ emb, float* __restrict__ F, int* __restrict__ cnt)
{
    if (blockIdx.x == 0 && threadIdx.x < NEXP) cnt[threadIdx.x] = 0;
    const int k = blockIdx.x;                 // 0..1024 (1024 = bias row)
    const int g = threadIdx.x >> 4;
    const int e = threadIdx.x & 15;
    const float* src = (k < HID) ? &Wmh[(size_t)k * HID] : bmh;
    float s = 0.f;
#pragma unroll
    for (int d = 0; d < DDIM; d++)
        s = fmaf(src[g * DDIM + d], emb[d * NEXP + e], s);
    F[(size_t)k * 256 + threadIdx.x] = s;
}

// ---------------------------------------------------------------------------
// Router v2: fp32 logits = x@F + fbias, K-split across thread pairs.
// Block = 256 threads = 128 sub-tokens x 2 K-halves (tid>>7). x rows for the
// block's 8 tokens staged in LDS (broadcast reads); F rows streamed from L2
// with an explicit 2-deep register prefetch (defeats the VGPR=36 serial-load
// codegen measured in r8: 6% VALU, 243 us). Upper half writes partials to
// LDS; lower half combines + softmax + top-2 + LDS-aggregated compaction.
// ---------------------------------------------------------------------------
__global__ __launch_bounds__(256) void router_F2(
    const float* __restrict__ x, const float* __restrict__ F,
    float2* __restrict__ rw, int* __restrict__ cnt, int* __restrict__ lists)
{
    __shared__ float xs[8 * HID];          // 32 KB: 8 token rows
    __shared__ float part[128][NEXP];      // 8 KB: upper-half partials
    __shared__ int lcnt[NEXP], gbase[NEXP];

    const int tid = threadIdx.x;
    const int blk = blockIdx.x;            // 512 blocks
    // stage x rows (coalesced float4): tokens blk*8 .. blk*8+7
    {
        const float4* src = (const float4*)(x + (size_t)blk * 8 * HID);
        float4* dst = (float4*)xs;
#pragma unroll
        for (int i = 0; i < 8; i++) dst[tid + i * 256] = src[tid + i * 256];
    }
    if (tid < NEXP) lcnt[tid] = 0;
    __syncthreads();

    const int sub = tid & 127;             // sub-token within block
    const int n   = blk * 128 + sub;       // global sub-token id
    const int tl  = sub >> 4;              // local token 0..7
    const int g   = sub & 15;              // head
    const int kh  = tid >> 7;              // K-half 0/1
    const int kbase = kh * 512;
    const float* Fg = F + g * 16;

    float lg[NEXP];
#pragma unroll
    for (int e = 0; e < NEXP; e++) lg[e] = 0.f;

    // 2-deep software pipeline over 512 F rows
    float4 c0, c1, c2, c3, d0, d1, d2, d3;
    {
        const float* r0 = Fg + (size_t)(kbase + 0) * 256;
        const float* r1 = Fg + (size_t)(kbase + 1) * 256;
        c0 = *(const float4*)&r0[0];  c1 = *(const float4*)&r0[4];
        c2 = *(const float4*)&r0[8];  c3 = *(const float4*)&r0[12];
        d0 = *(const float4*)&r1[0];  d1 = *(const float4*)&r1[4];
        d2 = *(const float4*)&r1[8];  d3 = *(const float4*)&r1[12];
    }
#define FMA16(XV) do {                                                       \
        lg[0]  = fmaf(XV, c0.x, lg[0]);  lg[1]  = fmaf(XV, c0.y, lg[1]);     \
        lg[2]  = fmaf(XV, c0.z, lg[2]);  lg[3]  = fmaf(XV, c0.w, lg[3]);     \
        lg[4]  = fmaf(XV, c1.x, lg[4]);  lg[5]  = fmaf(XV, c1.y, lg[5]);     \
        lg[6]  = fmaf(XV, c1.z, lg[6]);  lg[7]  = fmaf(XV, c1.w, lg[7]);     \
        lg[8]  = fmaf(XV, c2.x, lg[8]);  lg[9]  = fmaf(XV, c2.y, lg[9]);     \
        lg[10] = fmaf(XV, c2.z, lg[10]); lg[11] = fmaf(XV, c2.w, lg[11]);    \
        lg[12] = fmaf(XV, c3.x, lg[12]); lg[13] = fmaf(XV, c3.y, lg[13]);    \
        lg[14] = fmaf(XV, c3.z, lg[14]); lg[15] = fmaf(XV, c3.w, lg[15]);    \
    } while (0)

    for (int k = 0; k < 510; k++) {
        const float* rn = Fg + (size_t)(kbase + k + 2) * 256;
        const float4 n0 = *(const float4*)&rn[0];
        const float4 n1 = *(const float4*)&rn[4];
        const float4 n2 = *(const float4*)&rn[8];
        const float4 n3 = *(const float4*)&rn[12];
        const float xv = xs[tl * HID + kbase + k];
        FMA16(xv);
        c0 = d0; c1 = d1; c2 = d2; c3 = d3;
        d0 = n0; d1 = n1; d2 = n2; d3 = n3;
    }
    { const float xv = xs[tl * HID + kbase + 510]; FMA16(xv); }
    c0 = d0; c1 = d1; c2 = d2; c3 = d3;
    { const float xv = xs[tl * HID + kbase + 511]; FMA16(xv); }
#undef FMA16

    // upper half publishes partials
    if (kh == 1) {
#pragma unroll
        for (int e = 0; e < NEXP; e++) part[sub][e] = lg[e];
    }
    __syncthreads();

    int i1 = 0, i2 = 0, lp1 = 0, lp2 = 0;
    if (kh == 0) {
        const float* fb = Fg + (size_t)HID * 256;   // fbias row
#pragma unroll
        for (int e = 0; e < NEXP; e++) lg[e] += part[sub][e] + fb[e];

        float m = lg[0];
#pragma unroll
        for (int e = 1; e < NEXP; e++) m = fmaxf(m, lg[e]);
        float p[NEXP], den = 0.f;
#pragma unroll
        for (int e = 0; e < NEXP; e++) { p[e] = expf(lg[e] - m); den += p[e]; }
        float v1 = p[0];
#pragma unroll
        for (int e = 1; e < NEXP; e++) if (p[e] > v1) { v1 = p[e]; i1 = e; }
        i2 = (i1 == 0) ? 1 : 0; float v2 = p[i2];
#pragma unroll
        for (int e = 0; e < NEXP; e++)
            if (e != i1 && e != ((i1 == 0) ? 1 : 0) && p[e] > v2) { v2 = p[e]; i2 = e; }

        const float invd = 1.f / den;
        rw[n] = make_float2(v1 * invd, v2 * invd);
        lp1 = atomicAdd(&lcnt[i1], 1);
        lp2 = atomicAdd(&lcnt[i2], 1);
    }
    __syncthreads();
    if (tid < NEXP) gbase[tid] = atomicAdd(&cnt[tid], lcnt[tid]);
    __syncthreads();
    if (kh == 0) {
        lists[i1 * CAP + gbase[i1] + lp1] = n;              // slot 0
        lists[i2 * CAP + gbase[i2] + lp2] = n | 0x10000;    // slot 1
    }
}

// ---------------------------------------------------------------------------
// Expert GEMM over compacted lists (unchanged from the passing version).
// ---------------------------------------------------------------------------
__global__ __launch_bounds__(256) void expert_gemm(
    const float* __restrict__ h, const int* __restrict__ cnt,
    const int* __restrict__ lists, const float2* __restrict__ rw,
    const float* __restrict__ w1, const float* __restrict__ b1,
    const float* __restrict__ w2, const float* __restrict__ b2,
    const float* __restrict__ w3, const float* __restrict__ b3,
    float* __restrict__ pa, float* __restrict__ pb)
{
    const int e    = blockIdx.x;
    const int base = blockIdx.y * T_TILE;
    const int ne   = cnt[e];
    if (base >= ne) return;
    const int nt = min(T_TILE, ne - base);

    __shared__ float act0[T_TILE][DDIM];
    __shared__ float act1[T_TILE][DDIM];
    __shared__ int   toks[T_TILE];

    const int tid  = threadIdx.x;
    const int wave = tid >> 6;
    const int lane = tid & 63;
    const int jA   = lane & 31;
    const int half = lane >> 5;

    if (tid < T_TILE) toks[tid] = (tid < nt) ? lists[e * CAP + base + tid] : 0;
    __syncthreads();

#pragma unroll
    for (int p = 0; p < T_TILE / 16; p++) {
        const int r = p * 16 + (tid >> 4);
        const int c = (tid & 15) * 4;
        if (r < nt) {
            const int t = toks[r] & 0xffff;
            *(float4*)&act0[r][c] = *(const float4*)&h[(size_t)t * DDIM + c];
        }
    }
    __syncthreads();

    float wa[DDIM], wb[DDIM];

#define LOAD_W(WP, BP, BA, BB) do {                                          \
        const float* wp_ = (WP) + (size_t)e * DDIM * DDIM;                   \
        _Pragma("unroll")                                                    \
        for (int i = 0; i < DDIM; i++) {                                     \
            wa[i] = wp_[i * DDIM + jA];                                      \
            wb[i] = wp_[i * DDIM + jA + 32];                                 \
        }                                                                    \
        BA = (BP)[e * DDIM + jA]; BB = (BP)[e * DDIM + jA + 32];             \
    } while (0)

#define DOT2(SRC, TR, AA, BB2) do {                                          \
        float a0 = 0.f, a1s = 0.f, b0 = 0.f, b1s = 0.f;                      \
        _Pragma("unroll")                                                    \
        for (int i = 0; i < 32; i += 4) {                                    \
            const float4 v = *(const float4*)&SRC[TR][i];                    \
            a0 = fmaf(v.x, wa[i + 0], a0); b0 = fmaf(v.x, wb[i + 0], b0);    \
            a0 = fmaf(v.y, wa[i + 1], a0); b0 = fmaf(v.y, wb[i + 1], b0);    \
            a0 = fmaf(v.z, wa[i + 2], a0); b0 = fmaf(v.z, wb[i + 2], b0);    \
            a0 = fmaf(v.w, wa[i + 3], a0); b0 = fmaf(v.w, wb[i + 3], b0);    \
        }                                                                    \
        _Pragma("unroll")                                                    \
        for (int i = 32; i < 64; i += 4) {                                   \
            const float4 v = *(const float4*)&SRC[TR][i];                    \
            a1s = fmaf(v.x, wa[i + 0], a1s); b1s = fmaf(v.x, wb[i + 0], b1s);\
            a1s = fmaf(v.y, wa[i + 1], a1s); b1s = fmaf(v.y, wb[i + 1], b1s);\
            a1s = fmaf(v.z, wa[i + 2], a1s); b1s = fmaf(v.z, wb[i + 2], b1s);\
            a1s = fmaf(v.w, wa[i + 3], a1s); b1s = fmaf(v.w, wb[i + 3], b1s);\
        }                                                                    \
        AA = a0 + a1s; BB2 = b0 + b1s;                                       \
    } while (0)

    float ba, bb;
    LOAD_W(w1, b1, ba, bb);
#pragma unroll
    for (int p = 0; p < T_TILE / 8; p++) {
        const int tr = p * 8 + wave * 2 + half;
        float aA, aB;
        DOT2(act0, tr, aA, aB);
        act1[tr][jA]      = fmaxf(aA + ba, 0.f);
        act1[tr][jA + 32] = fmaxf(aB + bb, 0.f);
    }
    LOAD_W(w2, b2, ba, bb);
#pragma unroll
    for (int p = 0; p < T_TILE / 8; p++) {
        const int tr = p * 8 + wave * 2 + half;
        float aA, aB;
        DOT2(act1, tr, aA, aB);
        act0[tr][jA]      = fmaxf(aA + ba, 0.f);
        act0[tr][jA + 32] = fmaxf(aB + bb, 0.f);
    }
    LOAD_W(w3, b3, ba, bb);
#pragma unroll
    for (int p = 0; p < T_TILE / 8; p++) {
        const int tr = p * 8 + wave * 2 + half;
        float aA, aB;
        DOT2(act0, tr, aA, aB);
        if (tr < nt) {
            const int en = toks[tr];
            const int t  = en & 0xffff;
            const float2 wv = rw[t];
            const float wgt = (en & 0x10000) ? wv.y : wv.x;
            float* dst = (en & 0x10000) ? pb : pa;
            dst[(size_t)t * DDIM + jA]      = (aA + ba) * wgt;
            dst[(size_t)t * DDIM + jA + 32] = (aB + bb) * wgt;
        }
    }
#undef LOAD_W
#undef DOT2
}

// ---------------------------------------------------------------------------
// Transpose + bf16-convert: WT[n][k] = bf16(W[k][n]).  64x64 tiles.
// ---------------------------------------------------------------------------
__global__ __launch_bounds__(256) void transpose_bf16(
    const float* __restrict__ W, unsigned short* __restrict__ WT, int K, int N)
{
    __shared__ float tile[64][65];
    const int k0 = blockIdx.x * 64;
    const int n0 = blockIdx.y * 64;
    const int tid = threadIdx.x;
    const int tr = tid >> 4;
    const int tc = (tid & 15) * 4;
#pragma unroll
    for (int p = 0; p < 4; p++) {
        const int r = p * 16 + tr;
        const float4 v = *(const float4*)&W[(size_t)(k0 + r) * N + n0 + tc];
        tile[r][tc + 0] = v.x; tile[r][tc + 1] = v.y;
        tile[r][tc + 2] = v.z; tile[r][tc + 3] = v.w;
    }
    __syncthreads();
#pragma unroll
    for (int p = 0; p < 4; p++) {
        const int n = p * 16 + tr;
        ushort4 o;
        o.x = f2bf(tile[tc + 0][n]); o.y = f2bf(tile[tc + 1][n]);
        o.z = f2bf(tile[tc + 2][n]); o.w = f2bf(tile[tc + 3][n]);
        *(ushort4*)&WT[(size_t)(n0 + n) * K + k0 + tc] = o;
    }
}

// ---------------------------------------------------------------------------
// MFMA GEMM: C[M,N] = A[M,K] @ W[K,N] + bias, W given as WT[n][k] bf16.
// COMBINE: A := Aa + Ab elementwise during bf16 staging (GEMM2's top-2 fuse).
// r9 retile: 64x128 tile, grid (N/128, M/64) = 512 blocks = 2 blocks/CU
// (r8 showed 256-block launches = 1 wave/SIMD = no latency partner). 4 waves
// side-by-side in N: wave w owns cols w*32..+31, 4x2 frags of 16x16x32.
// Fragment mapping (m89-verified): A lane l holds A[l&15][(l>>4)*8+j];
// B lane l holds B[(l>>4)*8+j][l&15]; D col=l&15, row=(l>>4)*4+reg.
// ---------------------------------------------------------------------------
template <bool COMBINE>
__global__ __launch_bounds__(256) void gemm_mfma(
    const float* __restrict__ Aa, const float* __restrict__ Ab,
    const unsigned short* __restrict__ WT, const float* __restrict__ bias,
    float* __restrict__ C, int M, int N, int K)
{
    __shared__ unsigned short A_bf[64][KSTR];    // [m][k] (+pad)
    __shared__ unsigned short B_bf[128][KSTR];   // [n][k] (+pad)

    const int tid  = threadIdx.x;
    const int bm   = blockIdx.y * 64;
    const int bn   = blockIdx.x * 128;
    const int wave = tid >> 6;
    const int lane = tid & 63;
    const int wn   = wave * 32;             // wave col offset in tile
    const int r16  = lane & 15;
    const int g8   = (lane >> 4) * 8;

    const int arow = tid >> 2;              // A staging row 0..63
    const int akq  = (tid & 3) * 8;         // A staging k-offset (8 shorts)
    const int srow = tid >> 1;              // B staging row 0..127
    const int skh  = (tid & 1) * 16;        // B staging k-half

    f32x4 acc[4][2];
#pragma unroll
    for (int i = 0; i < 4; i++)
#pragma unroll
        for (int j = 0; j < 2; j++) acc[i][j] = (f32x4){0.f, 0.f, 0.f, 0.f};

    for (int k0 = 0; k0 < K; k0 += 32) {
        // stage A: rows bm..bm+63, one s16x8 per thread
        {
            const float* pA = Aa + (size_t)(bm + arow) * K + k0 + akq;
            float4 va0 = *(const float4*)&pA[0];
            float4 va1 = *(const float4*)&pA[4];
            if constexpr (COMBINE) {
                const float* pB = Ab + (size_t)(bm + arow) * K + k0 + akq;
                const float4 vb0 = *(const float4*)&pB[0];
                const float4 vb1 = *(const float4*)&pB[4];
                va0.x += vb0.x; va0.y += vb0.y; va0.z += vb0.z; va0.w += vb0.w;
                va1.x += vb1.x; va1.y += vb1.y; va1.z += vb1.z; va1.w += vb1.w;
            }
            unsigned short tmp[8];
            tmp[0] = f2bf(va0.x); tmp[1] = f2bf(va0.y);
            tmp[2] = f2bf(va0.z); tmp[3] = f2bf(va0.w);
            tmp[4] = f2bf(va1.x); tmp[5] = f2bf(va1.y);
            tmp[6] = f2bf(va1.z); tmp[7] = f2bf(va1.w);
            *(s16x8*)&A_bf[arow][akq] = *(s16x8*)&tmp[0];
        }
        // stage B: rows bn..bn+127, two s16x8 per thread
        {
            const unsigned short* pW = WT + (size_t)(bn + srow) * K + k0 + skh;
            *(s16x8*)&B_bf[srow][skh]     = *(const s16x8*)&pW[0];
            *(s16x8*)&B_bf[srow][skh + 8] = *(const s16x8*)&pW[8];
        }
        __syncthreads();

        s16x8 av[4], bv[2];
#pragma unroll
        for (int i = 0; i < 4; i++)
            av[i] = *(s16x8*)&A_bf[i * 16 + r16][g8];
#pragma unroll
        for (int j = 0; j < 2; j++)
            bv[j] = *(s16x8*)&B_bf[wn + j * 16 + r16][g8];
#pragma unroll
        for (int i = 0; i < 4; i++)
#pragma unroll
            for (int j = 0; j < 2; j++)
                acc[i][j] = __builtin_amdgcn_mfma_f32_16x16x32_bf16(
                    av[i], bv[j], acc[i][j], 0, 0, 0);
        __syncthreads();
    }

    // epilogue: D col=l&15, row=(l>>4)*4+reg
#pragma unroll
    for (int i = 0; i < 4; i++)
#pragma unroll
        for (int j = 0; j < 2; j++) {
            const int col = bn + wn + j * 16 + r16;
            const float bv2 = bias[col];
#pragma unroll
            for (int r = 0; r < 4; r++) {
                const int row = bm + i * 16 + (lane >> 4) * 4 + r;
                C[(size_t)row * N + col] = acc[i][j][r] + bv2;
            }
        }
}

// ---------------------------------------------------------------------------
extern "C" void kernel_launch(void* const* d_in, const int* in_sizes, int n_in,
                              void* d_out, int out_size, void* d_ws, size_t ws_size,
                              hipStream_t stream)
{
    const float* x    = (const float*)d_in[0];
    const float* Wmh  = (const float*)d_in[1];
    const float* bmh  = (const float*)d_in[2];
    const float* emb  = (const float*)d_in[3];
    const float* w1   = (const float*)d_in[4];
    const float* b1   = (const float*)d_in[5];
    const float* w2   = (const float*)d_in[6];
    const float* b2   = (const float*)d_in[7];
    const float* w3   = (const float*)d_in[8];
    const float* b3   = (const float*)d_in[9];
    const float* Wm   = (const float*)d_in[10];
    const float* bm   = (const float*)d_in[11];
    float* out = (float*)d_out;

    // ws (proven layout): h 16M | pa 16M | pb 16M | rw 512K | cnt 1K.
    // WmT (2MB, for GEMM2) aliases h after expert_gemm consumes it.
    // d_out scratch (dead before gemm2 overwrites d_out):
    //   lists @0 (4MB) | F @8M (1.05MB) | WmhT @12M (2MB).
    char* ws = (char*)d_ws;
    float*  h     = (float*)(ws);
    float*  pa    = (float*)(ws + (size_t)(16 << 20));
    float*  pb    = (float*)(ws + (size_t)(32 << 20));
    float2* rwp   = (float2*)(ws + (size_t)(48 << 20));
    int*    cntp  = (int*)  (ws + (size_t)(48 << 20) + (NSUB * 8));
    unsigned short* WmT = (unsigned short*)(ws);

    char* dob = (char*)d_out;
    int*            lists = (int*)dob;
    float*          F     = (float*)(dob + (size_t)(8 << 20));
    unsigned short* WmhT  = (unsigned short*)(dob + (size_t)(12 << 20));

    // 1) WmhT = bf16(Wmh^T);  F = [Wmh;bmh] @ emb (fp32) + cnt reset
    transpose_bf16<<<dim3(HID / 64, HID / 64), 256, 0, stream>>>(
        Wmh, WmhT, HID, HID);
    prep_F<<<HID + 1, 256, 0, stream>>>(Wmh, bmh, emb, F, cntp);

    // 2) h = x @ Wmh + bmh   (bf16 MFMA; h feeds only the expert MLP)
    gemm_mfma<false><<<dim3(HID / 128, MTOK / 64), 256, 0, stream>>>(
        x, nullptr, WmhT, bmh, h, MTOK, HID, HID);

    // 3) route on fp32 logits = x@F + fbias; compact per-expert lists
    router_F2<<<NSUB / 128, 256, 0, stream>>>(x, F, rwp, cntp, lists);

    // 4) sparse expert MLP -> slot planes pa, pb (h consumed here)
    expert_gemm<<<dim3(NEXP, CAP / T_TILE), 256, 0, stream>>>(
        h, cntp, lists, rwp, w1, b1, w2, b2, w3, b3, pa, pb);

    // 5) WmT = bf16(Wm^T)   (clobbers h — now dead)
    transpose_bf16<<<dim3(HID / 64, HID / 64), 256, 0, stream>>>(
        Wm, WmT, HID, HID);

    // 6) out = (pa + pb) @ Wm + bm   (bf16 MFMA, fused top-2 combine)
    gemm_mfma<true><<<dim3(HID / 128, MTOK / 64), 256, 0, stream>>>(
        pa, pb, WmT, bm, out, MTOK, HID, HID);
}